// Round 10
// baseline (90.899 us; speedup 1.0000x reference)
//
#include <hip/hip_runtime.h>
#include <hip/hip_bf16.h>

#define SEQ 2048
#define QSTR 4096
// (1/sqrt(128)) * log2(e)
#define CSCALE 0.1275174364688796f

typedef __attribute__((ext_vector_type(8)))  short short8;
typedef __attribute__((ext_vector_type(4)))  float f32x4;
typedef __attribute__((ext_vector_type(16))) float f32x16;

union PF8 { unsigned u[4]; short8 s; };

__device__ __forceinline__ unsigned short f2bf(float f) {
    union { __hip_bfloat16 b; unsigned short u; } cv;
    cv.b = __float2bfloat16(f);
    return cv.u;
}
__device__ __forceinline__ float bf2f(unsigned short u) {
    unsigned v = ((unsigned)u) << 16;
    return __builtin_bit_cast(float, v);
}

__device__ __forceinline__ void gload16(const unsigned short* g, unsigned short* l) {
    __builtin_amdgcn_global_load_lds(
        (const __attribute__((address_space(1))) void*)g,
        (__attribute__((address_space(3))) void*)l, 16, 0, 0);
}

// ---- prepass: K -> bf16 [hk][kv][d] ----
__global__ void prep_k(const float* __restrict__ Kg, unsigned short* __restrict__ Kb) {
    int gi = blockIdx.x * 256 + threadIdx.x;
    int kv = gi >> 8;
    int rem = gi & 255;
    int hk = rem >> 5;
    int d4 = rem & 31;
    f32x4 k4 = *(const f32x4*)(Kg + ((size_t)kv * 8 + hk) * 128 + 4 * d4);
    ushort4 u = make_ushort4(f2bf(k4[0]), f2bf(k4[1]), f2bf(k4[2]), f2bf(k4[3]));
    *(ushort4*)(Kb + ((size_t)hk * SEQ + kv) * 128 + 4 * d4) = u;
}

// ---- prepass: V -> bf16 transposed [hk][d][kv] ----
__global__ void prep_v(const float* __restrict__ Vg, unsigned short* __restrict__ Vtb) {
    const int hk  = blockIdx.x >> 5;
    const int kvb = blockIdx.x & 31;
    __shared__ unsigned short T[128][72];
    const int t = threadIdx.x;
    #pragma unroll
    for (int i = 0; i < 8; ++i) {
        int idx = t + 256 * i;
        int r = idx >> 5, d4 = idx & 31;
        f32x4 v = *(const f32x4*)(Vg + ((size_t)(kvb * 64 + r) * 8 + hk) * 128 + 4 * d4);
        T[4 * d4 + 0][r] = f2bf(v[0]);
        T[4 * d4 + 1][r] = f2bf(v[1]);
        T[4 * d4 + 2][r] = f2bf(v[2]);
        T[4 * d4 + 3][r] = f2bf(v[3]);
    }
    __syncthreads();
    #pragma unroll
    for (int i = 0; i < 8; ++i) {
        int idx = t + 256 * i;
        int d = idx >> 4, c4 = idx & 15;
        ushort4 u = *(ushort4*)&T[d][4 * c4];
        *(ushort4*)(Vtb + ((size_t)hk * 128 + d) * SEQ + kvb * 64 + 4 * c4) = u;
    }
}

__launch_bounds__(256, 2)
__global__ void attn_fwd(const float* __restrict__ Qg,
                         const unsigned short* __restrict__ Kb,
                         const unsigned short* __restrict__ Vtb,
                         float* __restrict__ Og) {
    const int bid = blockIdx.x;            // 512 blocks, all EXACTLY 33 steps
    const int p   = bid >> 5;              // 0..15
    const int h   = bid & 31;
    const int hk  = h >> 2;
    const int qbB = 31 - p;                // big 64-row q-block (phase B, first)
    const int qbA = p;                     // small (phase A)
    const int nsB = 32 - p;                // B steps; nsB + (p+1) == 33

    const int tid  = threadIdx.x;
    const int w    = tid >> 6;             // 0..3
    const int b    = w & 1;                // q band (32 rows)
    const int hf   = w >> 1;               // kv half (32 of 64)
    const int lane = tid & 63;
    const int q5   = lane & 31;
    const int t5   = lane >> 5;

    // Ks[buf][kv 64][d 128]: stored with granule ^= (row&15) (4-bit, 2-way max)
    // Vp[buf][r 64][256B]: packed V^T pair-rows: LDS[r][g] = V^T[2r+(g>>3)][kv-chunk (g&7)^(r&7)]
    __shared__ unsigned short Ks[2][64][128];
    __shared__ unsigned short Vp[2][64][128];
    __shared__ float mstat[2][4][32];
    __shared__ unsigned short Otb[32][136];   // bf16 partial-O exchange

    short8 qf[8];
    auto LOADQ = [&](int qb) __attribute__((always_inline)) {
        const float* qp = Qg + (size_t)(qb * 64 + 32 * b + q5) * QSTR + h * 128 + 8 * t5;
        #pragma unroll
        for (int st = 0; st < 8; ++st) {
            f32x4 a = *(const f32x4*)(qp + 16 * st);
            f32x4 c = *(const f32x4*)(qp + 16 * st + 4);
            short8 f;
            f[0] = (short)f2bf(a[0] * CSCALE); f[1] = (short)f2bf(a[1] * CSCALE);
            f[2] = (short)f2bf(a[2] * CSCALE); f[3] = (short)f2bf(a[3] * CSCALE);
            f[4] = (short)f2bf(c[0] * CSCALE); f[5] = (short)f2bf(c[1] * CSCALE);
            f[6] = (short)f2bf(c[2] * CSCALE); f[7] = (short)f2bf(c[3] * CSCALE);
            qf[st] = f;
        }
    };

    auto ISSUE = [&](int kv0, int bb) __attribute__((always_inline)) {
        #pragma unroll
        for (int p4 = 0; p4 < 4; ++p4) {
            int row = 16 * w + 4 * p4 + (lane >> 4);
            const unsigned short* g = Kb +
                ((size_t)hk * SEQ + kv0 + row) * 128 + 8 * ((lane & 15) ^ (row & 15));
            gload16(g, &Ks[bb][16 * w + 4 * p4][0]);
        }
        #pragma unroll
        for (int p4 = 0; p4 < 4; ++p4) {
            int r  = 16 * w + 4 * p4 + (lane >> 4);
            int gg = lane & 15;
            int d  = 2 * r + (gg >> 3);
            int c  = (gg & 7) ^ (r & 7);
            const unsigned short* g = Vtb +
                ((size_t)hk * 128 + d) * SEQ + kv0 + 8 * c;
            gload16(g, &Vp[bb][16 * w + 4 * p4][0]);
        }
    };

    f32x16 oacc[4];
    float m, l;
    auto RESET = [&]() __attribute__((always_inline)) {
        #pragma unroll
        for (int dt = 0; dt < 4; ++dt)
            #pragma unroll
            for (int r = 0; r < 16; ++r) oacc[dt][r] = 0.f;
        m = -1e30f; l = 0.f;
    };

    // phase-end: 2-way kv-half combine + coalesced store (Otb turns, bf16)
    auto EPI = [&](int qb) __attribute__((always_inline)) {
        if (t5 == 0) mstat[0][w][q5] = m;
        asm volatile("s_waitcnt lgkmcnt(0)" ::: "memory");
        __builtin_amdgcn_sched_barrier(0);
        __builtin_amdgcn_s_barrier();
        const float mo = mstat[0][w ^ 2][q5];
        const float M  = fmaxf(m, mo);
        const float sc = exp2f(m - M);
        #pragma unroll
        for (int dt = 0; dt < 4; ++dt)
            #pragma unroll
            for (int r = 0; r < 16; ++r) oacc[dt][r] *= sc;
        const float lp = l * sc;
        if (t5 == 0) mstat[1][w][q5] = lp;
        asm volatile("s_waitcnt lgkmcnt(0)" ::: "memory");
        __builtin_amdgcn_sched_barrier(0);
        __builtin_amdgcn_s_barrier();
        const float rl = 1.0f / (lp + mstat[1][w ^ 2][q5]);

        #pragma unroll 1
        for (int bb = 0; bb < 2; ++bb) {
            if (w == 2 + bb) {            // hf==1 wave of band bb: publish partial
                #pragma unroll
                for (int dt = 0; dt < 4; ++dt)
                    #pragma unroll
                    for (int ii = 0; ii < 4; ++ii) {
                        ushort4 u = make_ushort4(
                            f2bf(oacc[dt][4 * ii + 0]), f2bf(oacc[dt][4 * ii + 1]),
                            f2bf(oacc[dt][4 * ii + 2]), f2bf(oacc[dt][4 * ii + 3]));
                        *(ushort4*)&Otb[q5][32 * dt + 8 * ii + 4 * t5] = u;
                    }
            }
            asm volatile("s_waitcnt lgkmcnt(0)" ::: "memory");
            __builtin_amdgcn_sched_barrier(0);
            __builtin_amdgcn_s_barrier();
            if (w == bb) {                // hf==0 wave: combine + normalize
                #pragma unroll
                for (int dt = 0; dt < 4; ++dt)
                    #pragma unroll
                    for (int ii = 0; ii < 4; ++ii) {
                        ushort4 o1 = *(ushort4*)&Otb[q5][32 * dt + 8 * ii + 4 * t5];
                        ushort4 u = make_ushort4(
                            f2bf((oacc[dt][4 * ii + 0] + bf2f(o1.x)) * rl),
                            f2bf((oacc[dt][4 * ii + 1] + bf2f(o1.y)) * rl),
                            f2bf((oacc[dt][4 * ii + 2] + bf2f(o1.z)) * rl),
                            f2bf((oacc[dt][4 * ii + 3] + bf2f(o1.w)) * rl));
                        *(ushort4*)&Otb[q5][32 * dt + 8 * ii + 4 * t5] = u;
                    }
            }
            asm volatile("s_waitcnt lgkmcnt(0)" ::: "memory");
            __builtin_amdgcn_sched_barrier(0);
            __builtin_amdgcn_s_barrier();
            {   // all 256 threads: coalesced fp32 store of band bb rows
                const int r  = tid >> 3;
                const int c0 = 16 * (tid & 7);
                float* og = Og + (size_t)(qb * 64 + 32 * bb + r) * QSTR + h * 128 + c0;
                #pragma unroll
                for (int j = 0; j < 4; ++j) {
                    ushort4 u = *(ushort4*)&Otb[r][c0 + 4 * j];
                    f32x4 v;
                    v[0] = bf2f(u.x); v[1] = bf2f(u.y);
                    v[2] = bf2f(u.z); v[3] = bf2f(u.w);
                    *(f32x4*)(og + 4 * j) = v;
                }
            }
            asm volatile("s_waitcnt lgkmcnt(0)" ::: "memory");
            __builtin_amdgcn_sched_barrier(0);
            __builtin_amdgcn_s_barrier();
        }
    };

    LOADQ(qbB);
    #pragma unroll
    for (int st = 0; st < 8; ++st) asm volatile("" :: "v"(qf[st]));
    asm volatile("s_waitcnt vmcnt(0)" ::: "memory");
    RESET();

    ISSUE(0, 0);
    ISSUE(64, 1);     // nsB >= 17, both prologue tiles are phase-B

    for (int s = 0; s < 33; ++s) {
        if (s == nsB) {              // phase switch B -> A
            LOADQ(qbA);              // hides under EPI
            EPI(qbB);
            RESET();
        }
        const bool isB = (s < nsB);
        const int kv0  = isB ? 64 * s : 64 * (s - nsB);
        const int qb   = isB ? qbB : qbA;
        const int q0w  = qb * 64 + 32 * b;
        const int buf  = s & 1;

        if (s + 1 < 33) asm volatile("s_waitcnt vmcnt(8)" ::: "memory");
        else            asm volatile("s_waitcnt vmcnt(0)" ::: "memory");
        __builtin_amdgcn_s_barrier();

        const int kvh = kv0 + 32 * hf;        // this wave's 32-kv chunk base
        if (kvh <= q0w + 31) {
            // ---- S^T = K Q^T : D[row=kv][col=q5] ----
            f32x16 sac;
            #pragma unroll
            for (int r = 0; r < 16; ++r) sac[r] = 0.f;
            __builtin_amdgcn_s_setprio(1);
            #pragma unroll
            for (int st = 0; st < 8; ++st) {
                short8 kf = *(const short8*)
                    &Ks[buf][32 * hf + q5][8 * ((2 * st + t5) ^ (q5 & 15))];
                sac = __builtin_amdgcn_mfma_f32_32x32x16_bf16(kf, qf[st], sac, 0, 0, 0);
            }
            __builtin_amdgcn_s_setprio(0);

            // ---- mask (diagonal only) ----
            if (kvh + 31 > q0w) {
                const int qrow = q0w + q5;
                #pragma unroll
                for (int r = 0; r < 16; ++r) {
                    int kv = kvh + (r & 3) + 8 * (r >> 2) + 4 * t5;
                    if (kv > qrow) sac[r] = -1e30f;
                }
            }

            // ---- row max: depth-4 tree + one cross-lane ----
            float m8[8], m4[4], m2[2];
            #pragma unroll
            for (int i = 0; i < 8; ++i) m8[i] = fmaxf(sac[i], sac[i + 8]);
            #pragma unroll
            for (int i = 0; i < 4; ++i) m4[i] = fmaxf(m8[i], m8[i + 4]);
            m2[0] = fmaxf(m4[0], m4[2]); m2[1] = fmaxf(m4[1], m4[3]);
            float mx = fmaxf(m2[0], m2[1]);
            mx = fmaxf(mx, __shfl_xor(mx, 32));

            // ---- defer-max (T13) ----
            const bool skip = __all(mx <= m + 11.0f);
            float fac = 1.0f;
            if (!skip) {
                float mn = fmaxf(m, mx);
                fac = exp2f(m - mn);
                m = mn;
            }

            // ---- P = 2^(S-m); depth-4 tree sum ----
            #pragma unroll
            for (int r = 0; r < 16; ++r) sac[r] = exp2f(sac[r] - m);
            float s8[8], s4[4], s2[2];
            #pragma unroll
            for (int i = 0; i < 8; ++i) s8[i] = sac[i] + sac[i + 8];
            #pragma unroll
            for (int i = 0; i < 4; ++i) s4[i] = s8[i] + s8[i + 4];
            s2[0] = s4[0] + s4[2]; s2[1] = s4[1] + s4[3];
            float ps = s2[0] + s2[1];
            ps += __shfl_xor(ps, 32);
            if (!skip) {
                l = l * fac + ps;
                #pragma unroll
                for (int dt = 0; dt < 4; ++dt)
                    #pragma unroll
                    for (int r = 0; r < 16; ++r) oacc[dt][r] *= fac;
            } else {
                l += ps;
            }

            // ---- pack P pairs to bf16x2 ----
            unsigned pkw[8];
            #pragma unroll
            for (int rp = 0; rp < 8; ++rp)
                pkw[rp] = (unsigned)f2bf(sac[2 * rp]) |
                          ((unsigned)f2bf(sac[2 * rp + 1]) << 16);

            // ---- redistribute to PV B-fragments (cross-half only) ----
            unsigned xp[8];
            #pragma unroll
            for (int i = 0; i < 8; ++i)
                xp[i] = (unsigned)__shfl_xor((int)pkw[i], 32);

            PF8 pf[2];
            #pragma unroll
            for (int ks = 0; ks < 2; ++ks) {
                #pragma unroll
                for (int j = 0; j < 4; ++j) {
                    const int ib = (j & 1) + 4 * ks;
                    const unsigned own_lo = pkw[ib];
                    const unsigned own_hi = pkw[ib + 2];
                    const unsigned par_lo = xp[ib];
                    const unsigned par_hi = xp[ib + 2];
                    pf[ks].u[j] = (j < 2) ? (t5 ? par_hi : own_lo)
                                          : (t5 ? own_hi : par_lo);
                }
            }

            // ---- O^T += V^T P (packed-V read, 2-way max banks) ----
            __builtin_amdgcn_s_setprio(1);
            #pragma unroll
            for (int dt = 0; dt < 4; ++dt) {
                #pragma unroll
                for (int ks = 0; ks < 2; ++ks) {
                    const int gg = 8 * (q5 & 1) +
                        ((4 * hf + 2 * ks + t5) ^ ((q5 >> 1) & 7));
                    short8 vf = *(const short8*)
                        &Vp[buf][16 * dt + (q5 >> 1)][8 * gg];
                    oacc[dt] = __builtin_amdgcn_mfma_f32_32x32x16_bf16(vf, pf[ks].s, oacc[dt], 0, 0, 0);
                }
            }
            __builtin_amdgcn_s_setprio(0);
        }

        asm volatile("" ::: "memory");
        __builtin_amdgcn_s_barrier();
        if (s + 2 < 33) {
            const int s2 = s + 2;
            ISSUE((s2 < nsB) ? 64 * s2 : 64 * (s2 - nsB), s & 1);
        }
    }

    EPI(qbA);
}

extern "C" void kernel_launch(void* const* d_in, const int* in_sizes, int n_in,
                              void* d_out, int out_size, void* d_ws, size_t ws_size,
                              hipStream_t stream) {
    const float* q = (const float*)d_in[0];
    const float* k = (const float*)d_in[1];
    const float* v = (const float*)d_in[2];
    float* out = (float*)d_out;
    unsigned short* Kb  = (unsigned short*)d_ws;                 // 4 MB
    unsigned short* Vtb = Kb + (size_t)8 * SEQ * 128;            // 4 MB
    prep_k<<<dim3(2048), 256, 0, stream>>>(k, Kb);
    prep_v<<<dim3(256), 256, 0, stream>>>(v, Vtb);
    attn_fwd<<<dim3(512), 256, 0, stream>>>(q, Kb, Vtb, out);
}